// Round 8
// baseline (359.263 us; speedup 1.0000x reference)
//
#include <hip/hip_runtime.h>
#include <hip/hip_bf16.h>

// Problem constants (fixed by reference)
#define L_SEQ 1024
#define B_DLG 128
#define D_DIM 256
#define BM 32            // rows per tile
#define THREADS 512      // 8 waves
#define KSTEPS 8         // 256 / 32
#define TPB 4            // tiles per block (persistent)
#define NTILES (L_SEQ / BM)                   // 32 row-tiles per dialogue
#define NBLK (B_DLG * NTILES / TPB)           // 1024 blocks
#define OBPAD 778        // fp32 stride for out-staging

typedef __attribute__((ext_vector_type(8))) short short8;   // 8 bf16 (4 VGPRs)
typedef __attribute__((ext_vector_type(4))) float f32x4;    // MFMA accumulator

__device__ __forceinline__ unsigned short f_to_bfbits(float f) {
    unsigned int u = __float_as_uint(f);
    unsigned int r = (u + 0x7FFFu + ((u >> 16) & 1u)) >> 16;   // RNE
    return (unsigned short)r;
}
__device__ __forceinline__ float fast_tanh(float x) {
    return 1.0f - 2.0f / (__expf(2.0f * x) + 1.0f);
}
__device__ __forceinline__ float fast_sigmoid(float x) {
    return 1.0f / (1.0f + __expf(-x));
}
__device__ __forceinline__ float dot4(float4 x, float4 w) {
    return x.x * w.x + x.y * w.y + x.z * w.z + x.w * w.w;
}

// LDS-only barrier: orders LDS producer->consumer across waves WITHOUT
// draining vmcnt (global loads stay in flight across it). All inter-wave
// hazards in fused_kernel are LDS; global loads are same-wave consumed
// (compiler inserts vmcnt waits at use), global stores are never read.
__device__ __forceinline__ void lds_barrier() {
    asm volatile("s_waitcnt lgkmcnt(0)" ::: "memory");
    __builtin_amdgcn_s_barrier();
    __builtin_amdgcn_sched_barrier(0);
}

// Convert the three (256x256) fp32 modality weights to bf16 AND pre-arrange in
// MFMA-fragment order so the GEMM's B-loads are lane-linear (fully coalesced):
//   dst chunk (16B = 8 bf16) = ((mod*16 + cg)*8 + ks)*64 + kblk*16 + l15
//   holds src col = cg*16 + l15, k = ks*32 + kblk*8 .. +8
__global__ void wconv_kernel(const float* __restrict__ wa,
                             const float* __restrict__ wv,
                             const float* __restrict__ wl,
                             unsigned short* __restrict__ wb) {
    int i = blockIdx.x * blockDim.x + threadIdx.x;   // src chunk id, 0..24575
    int mod  = i >> 13;                              // 8192 chunks per modality
    int r    = i & 8191;                             // col*32 + ks*4 + kblk
    int col  = r >> 5;
    int ks   = (r >> 2) & 7;
    int kblk = r & 3;
    const float* src = (mod == 0) ? wa : (mod == 1) ? wv : wl;
    const float4* s = (const float4*)(src + col * 256 + ks * 32 + kblk * 8);
    float4 lo = s[0], hi = s[1];
    short8 pk;
    pk[0] = (short)f_to_bfbits(lo.x); pk[1] = (short)f_to_bfbits(lo.y);
    pk[2] = (short)f_to_bfbits(lo.z); pk[3] = (short)f_to_bfbits(lo.w);
    pk[4] = (short)f_to_bfbits(hi.x); pk[5] = (short)f_to_bfbits(hi.y);
    pk[6] = (short)f_to_bfbits(hi.z); pk[7] = (short)f_to_bfbits(hi.w);
    int dst = mod * 8192 + (((col >> 4) * 8 + ks) << 6) + kblk * 16 + (col & 15);
    *(short8*)(wb + dst * 8) = pk;
}

__global__ __attribute__((amdgpu_waves_per_eu(4, 4))) __launch_bounds__(THREADS)
void fused_kernel(const float* __restrict__ a,
                  const float* __restrict__ v,
                  const float* __restrict__ l,
                  const unsigned short* __restrict__ wbf,   // packed fragments
                  const float* __restrict__ ba,
                  const float* __restrict__ bv,
                  const float* __restrict__ bl,
                  const float* __restrict__ wav, const float* __restrict__ bav,
                  const float* __restrict__ wal, const float* __restrict__ bal,
                  const float* __restrict__ wvl, const float* __restrict__ bvl,
                  float* __restrict__ out) {
    // Union: A-tiles (3*32*256*2 = 49152 B) aliased with out-staging
    // (16*778*4 = 49792 B). A-tiles are dead by the time OB is written.
    __shared__ __align__(16) char lds_raw[16 * OBPAD * 4];
    __shared__ __align__(16) float lds_gw[3][3 * D_DIM];   // 9 KiB
    __shared__ float lds_z[3][BM];
#define LDS_A  ((unsigned short (*)[BM][D_DIM])lds_raw)
#define LDS_OB ((float (*)[OBPAD])lds_raw)

    const int tid  = threadIdx.x;
    const int wave = tid >> 6;
    const int lane = tid & 63;
    const int b    = blockIdx.x >> 3;                    // dialogue 0..127
    const int t00  = (blockIdx.x & 7) * (TPB * BM);      // block's 128-row range

    // ---- loop-invariant: gate weights -> LDS ----
    for (int i = tid; i < 3 * 3 * D_DIM; i += THREADS) {
        int g = i / (3 * D_DIM);
        int k = i - g * (3 * D_DIM);
        const float* gw = (g == 0) ? wav : (g == 1) ? wal : wvl;
        lds_gw[g][k] = gw[k];
    }
    const float gbav = bav[0], gbal = bal[0], gbvl = bvl[0];

    // ---- epilogue biases (per-thread scalars) ----
    const int l15 = lane & 15;
    const int kblk = lane >> 4;
    const int colbase = wave * 32;
    const int col0 = colbase + l15, col1 = colbase + 16 + l15;
    const float bba0 = ba[col0], bba1 = ba[col1];
    const float bbv0 = bv[col0], bbv1 = bv[col1];
    const float bbl0 = bl[col0], bbl1 = bl[col1];

    const int swz  = (wave & 7) << 4;
    const int boff = (lane * 8) ^ swz;
    const int k0   = lane * 4;

    // ---- prologue: load tile 0 into registers ----
    float4 fa[4], fv[4], fl[4];
#pragma unroll
    for (int i = 0; i < 4; ++i) {
        const int row = wave + 8 * i;
        const size_t gbase = ((size_t)(t00 + row) * B_DLG + b) * D_DIM + lane * 4;
        fa[i] = *(const float4*)(a + gbase);
        fv[i] = *(const float4*)(v + gbase);
        fl[i] = *(const float4*)(l + gbase);
    }

#pragma unroll 1
    for (int it = 0; it < TPB; ++it) {
        const int t0 = t00 + it * BM;
        lds_barrier();   // (A) prev OB reads done / gw visible; pack may write

        // ---------------- pack -> LDS (swizzled) + fused gates ----------------
        {
            float4 gav0 = *(const float4*)&lds_gw[0][k0];
            float4 gav1 = *(const float4*)&lds_gw[0][256 + k0];
            float4 gav2 = *(const float4*)&lds_gw[0][512 + k0];
            float4 gal0 = *(const float4*)&lds_gw[1][k0];
            float4 gal1 = *(const float4*)&lds_gw[1][256 + k0];
            float4 gal2 = *(const float4*)&lds_gw[1][512 + k0];
            float4 gvl0 = *(const float4*)&lds_gw[2][k0];
            float4 gvl1 = *(const float4*)&lds_gw[2][256 + k0];
            float4 gvl2 = *(const float4*)&lds_gw[2][512 + k0];
#pragma unroll
            for (int i = 0; i < 4; ++i) {
                const int row = wave + 8 * i;
                ushort4 pa, pv, pl;
                pa.x = f_to_bfbits(fa[i].x); pa.y = f_to_bfbits(fa[i].y);
                pa.z = f_to_bfbits(fa[i].z); pa.w = f_to_bfbits(fa[i].w);
                pv.x = f_to_bfbits(fv[i].x); pv.y = f_to_bfbits(fv[i].y);
                pv.z = f_to_bfbits(fv[i].z); pv.w = f_to_bfbits(fv[i].w);
                pl.x = f_to_bfbits(fl[i].x); pl.y = f_to_bfbits(fl[i].y);
                pl.z = f_to_bfbits(fl[i].z); pl.w = f_to_bfbits(fl[i].w);
                *(ushort4*)((char*)&LDS_A[0][row][0] + boff) = pa;
                *(ushort4*)((char*)&LDS_A[1][row][0] + boff) = pv;
                *(ushort4*)((char*)&LDS_A[2][row][0] + boff) = pl;

                float4 pav, pal, pvl;
                pav.x = fa[i].x * fv[i].x; pav.y = fa[i].y * fv[i].y;
                pav.z = fa[i].z * fv[i].z; pav.w = fa[i].w * fv[i].w;
                pal.x = fa[i].x * fl[i].x; pal.y = fa[i].y * fl[i].y;
                pal.z = fa[i].z * fl[i].z; pal.w = fa[i].w * fl[i].w;
                pvl.x = fv[i].x * fl[i].x; pvl.y = fv[i].y * fl[i].y;
                pvl.z = fv[i].z * fl[i].z; pvl.w = fv[i].w * fl[i].w;
                float s_av = dot4(fa[i], gav0) + dot4(fv[i], gav1) + dot4(pav, gav2);
                float s_al = dot4(fa[i], gal0) + dot4(fl[i], gal1) + dot4(pal, gal2);
                float s_vl = dot4(fv[i], gvl0) + dot4(fl[i], gvl1) + dot4(pvl, gvl2);
#pragma unroll
                for (int off = 1; off < 64; off <<= 1) {
                    s_av += __shfl_xor(s_av, off);
                    s_al += __shfl_xor(s_al, off);
                    s_vl += __shfl_xor(s_vl, off);
                }
                if (lane == 0) {
                    lds_z[0][row] = fast_sigmoid(s_av + gbav);
                    lds_z[1][row] = fast_sigmoid(s_al + gbal);
                    lds_z[2][row] = fast_sigmoid(s_vl + gbvl);
                }
            }
        }

        // ---- prefetch next tile, part 1 (rows 0-1): 6 float4 live across GEMM ----
        const int nt0 = t0 + BM;
        if (it + 1 < TPB) {
#pragma unroll
            for (int i = 0; i < 2; ++i) {
                const int row = wave + 8 * i;
                const size_t gbase = ((size_t)(nt0 + row) * B_DLG + b) * D_DIM + lane * 4;
                fa[i] = *(const float4*)(a + gbase);
                fv[i] = *(const float4*)(v + gbase);
                fl[i] = *(const float4*)(l + gbase);
            }
        }

        lds_barrier();   // (B) A-tile + z ready for all waves

        // ---------------- GEMM K-loop ----------------
        f32x4 acc[3][2][2];
#pragma unroll
        for (int m = 0; m < 3; ++m)
#pragma unroll
            for (int mt = 0; mt < 2; ++mt)
#pragma unroll
                for (int ct = 0; ct < 2; ++ct)
                    acc[m][mt][ct] = (f32x4){0.f, 0.f, 0.f, 0.f};

#pragma unroll 2
        for (int ks = 0; ks < KSTEPS; ++ks) {
            int kbyte = ks * 64 + kblk * 16;
#pragma unroll
            for (int mod = 0; mod < 3; ++mod) {
                short8 afrag[2];
#pragma unroll
                for (int mt = 0; mt < 2; ++mt) {
                    int row = mt * 16 + l15;
                    int bo = kbyte ^ ((row & 7) << 4);
                    afrag[mt] = *(const short8*)((const char*)&LDS_A[mod][row][0] + bo);
                }
#pragma unroll
                for (int ct = 0; ct < 2; ++ct) {
                    const unsigned short* bp = wbf +
                        ((size_t)(((mod * 16 + wave * 2 + ct) * 8 + ks) * 64) + lane) * 8;
                    short8 bfrag = *(const short8*)bp;
#pragma unroll
                    for (int mt = 0; mt < 2; ++mt)
                        acc[mod][mt][ct] = __builtin_amdgcn_mfma_f32_16x16x32_bf16(
                            afrag[mt], bfrag, acc[mod][mt][ct], 0, 0, 0);
                }
            }
        }

        // ---- prefetch next tile, part 2 (rows 2-3): overlaps epilogue ----
        if (it + 1 < TPB) {
#pragma unroll
            for (int i = 2; i < 4; ++i) {
                const int row = wave + 8 * i;
                const size_t gbase = ((size_t)(nt0 + row) * B_DLG + b) * D_DIM + lane * 4;
                fa[i] = *(const float4*)(a + gbase);
                fv[i] = *(const float4*)(v + gbase);
                fl[i] = *(const float4*)(l + gbase);
            }
        }

        // ---------------- epilogue: gate -> LDS out-stage -> wide stores ------
        const size_t rowbase = (size_t)b * L_SEQ + t0;
#pragma unroll
        for (int half = 0; half < 2; ++half) {
            lds_barrier();   // (C) A-tile reads (half0) / OB reads (half1) done
            const int mt = half;
#pragma unroll
            for (int ct = 0; ct < 2; ++ct) {
                const int col = (ct == 0) ? col0 : col1;
                const float bba = (ct == 0) ? bba0 : bba1;
                const float bbv = (ct == 0) ? bbv0 : bbv1;
                const float bbl = (ct == 0) ? bbl0 : bbl1;
#pragma unroll
                for (int r = 0; r < 4; ++r) {
                    const int rh = kblk * 4 + r;           // row within half
                    float ta = fast_tanh(acc[0][mt][ct][r] + bba);
                    float tv = fast_tanh(acc[1][mt][ct][r] + bbv);
                    float tl = fast_tanh(acc[2][mt][ct][r] + bbl);
                    float zav = lds_z[0][mt * 16 + rh];
                    float zal = lds_z[1][mt * 16 + rh];
                    float zvl = lds_z[2][mt * 16 + rh];
                    LDS_OB[rh][col]             = zav * ta + (1.f - zav) * tv;
                    LDS_OB[rh][D_DIM + col]     = zal * ta + (1.f - zal) * tl;
                    LDS_OB[rh][2 * D_DIM + col] = zvl * tv + (1.f - zvl) * tl;
                }
            }
            lds_barrier();   // (D) OB complete
            // wide coalesced stores: each wave-instr writes 1KB contiguous
#pragma unroll
            for (int r2 = 0; r2 < 2; ++r2) {
                const int row = wave * 2 + r2;             // 0..15 within half
#pragma unroll
                for (int s = 0; s < 3; ++s) {
                    float4 val = *(const float4*)&LDS_OB[row][s * D_DIM + lane * 4];
                    *(float4*)(out + (rowbase + half * 16 + row) * (3 * D_DIM)
                                   + s * D_DIM + lane * 4) = val;
                }
            }
        }
    }
#undef LDS_A
#undef LDS_OB
}

extern "C" void kernel_launch(void* const* d_in, const int* in_sizes, int n_in,
                              void* d_out, int out_size, void* d_ws, size_t ws_size,
                              hipStream_t stream) {
    const float* a   = (const float*)d_in[0];
    const float* v   = (const float*)d_in[1];
    const float* l   = (const float*)d_in[2];
    // d_in[3] = lengths (all == L, static shape -> unused)
    const float* Wa  = (const float*)d_in[4];
    const float* ba  = (const float*)d_in[5];
    const float* Wv  = (const float*)d_in[6];
    const float* bv  = (const float*)d_in[7];
    const float* Wl  = (const float*)d_in[8];
    const float* bl  = (const float*)d_in[9];
    const float* Wav = (const float*)d_in[10];
    const float* bav = (const float*)d_in[11];
    const float* Wal = (const float*)d_in[12];
    const float* bal = (const float*)d_in[13];
    const float* Wvl = (const float*)d_in[14];
    const float* bvl = (const float*)d_in[15];
    float* out = (float*)d_out;

    unsigned short* wb = (unsigned short*)d_ws;   // needs 3*65536*2 = 384 KiB

    hipLaunchKernelGGL(wconv_kernel, dim3(96), dim3(256), 0, stream, Wa, Wv, Wl, wb);
    hipLaunchKernelGGL(fused_kernel, dim3(NBLK), dim3(THREADS), 0, stream,
                       a, v, l, wb, ba, bv, bl, Wav, bav, Wal, bal, Wvl, bvl, out);
}

// Round 9
// 292.506 us; speedup vs baseline: 1.2282x; 1.2282x over previous
//
#include <hip/hip_runtime.h>
#include <hip/hip_bf16.h>

// Problem constants (fixed by reference)
#define L_SEQ 1024
#define B_DLG 128
#define D_DIM 256
#define BM 16            // rows per block tile
#define THREADS 512      // 8 waves
#define KSTEPS 8         // 256 / 32
#define NTILES (L_SEQ / BM)             // 64 row-tiles per dialogue
#define NBLK (B_DLG * NTILES)           // 8192 blocks
#define OBROW 36         // dwords per OB row: 16B-aligned, bank-spread (36%32=4)

typedef __attribute__((ext_vector_type(8))) short short8;   // 8 bf16 (4 VGPRs)
typedef __attribute__((ext_vector_type(4))) float f32x4;    // MFMA accumulator

__device__ __forceinline__ unsigned short f_to_bfbits(float f) {
    unsigned int u = __float_as_uint(f);
    unsigned int r = (u + 0x7FFFu + ((u >> 16) & 1u)) >> 16;   // RNE
    return (unsigned short)r;
}
__device__ __forceinline__ float fast_tanh(float x) {
    return 1.0f - 2.0f / (__expf(2.0f * x) + 1.0f);
}
__device__ __forceinline__ float fast_sigmoid(float x) {
    return 1.0f / (1.0f + __expf(-x));
}
__device__ __forceinline__ float dot4(float4 x, float4 w) {
    return x.x * w.x + x.y * w.y + x.z * w.z + x.w * w.w;
}

// Convert the three (256x256) fp32 modality weights to bf16 AND pre-arrange in
// MFMA-fragment order so the GEMM's B-loads are lane-linear (fully coalesced):
//   dst chunk (16B = 8 bf16) = ((mod*16 + cg)*8 + ks)*64 + kblk*16 + l15
//   holds src col = cg*16 + l15, k = ks*32 + kblk*8 .. +8
__global__ void wconv_kernel(const float* __restrict__ wa,
                             const float* __restrict__ wv,
                             const float* __restrict__ wl,
                             unsigned short* __restrict__ wb) {
    int i = blockIdx.x * blockDim.x + threadIdx.x;   // src chunk id, 0..24575
    int mod  = i >> 13;                              // 8192 chunks per modality
    int r    = i & 8191;                             // col*32 + ks*4 + kblk
    int col  = r >> 5;
    int ks   = (r >> 2) & 7;
    int kblk = r & 3;
    const float* src = (mod == 0) ? wa : (mod == 1) ? wv : wl;
    const float4* s = (const float4*)(src + col * 256 + ks * 32 + kblk * 8);
    float4 lo = s[0], hi = s[1];
    short8 pk;
    pk[0] = (short)f_to_bfbits(lo.x); pk[1] = (short)f_to_bfbits(lo.y);
    pk[2] = (short)f_to_bfbits(lo.z); pk[3] = (short)f_to_bfbits(lo.w);
    pk[4] = (short)f_to_bfbits(hi.x); pk[5] = (short)f_to_bfbits(hi.y);
    pk[6] = (short)f_to_bfbits(hi.z); pk[7] = (short)f_to_bfbits(hi.w);
    int dst = mod * 8192 + (((col >> 4) * 8 + ks) << 6) + kblk * 16 + (col & 15);
    *(short8*)(wb + dst * 8) = pk;
}

__global__ __launch_bounds__(THREADS, 4)
void fused_kernel(const float* __restrict__ a,
                  const float* __restrict__ v,
                  const float* __restrict__ l,
                  const unsigned short* __restrict__ wbf,   // packed fragments
                  const float* __restrict__ ba,
                  const float* __restrict__ bv,
                  const float* __restrict__ bl,
                  const float* __restrict__ wav, const float* __restrict__ bav,
                  const float* __restrict__ wal, const float* __restrict__ bal,
                  const float* __restrict__ wvl, const float* __restrict__ bvl,
                  float* __restrict__ out) {
    // A-tile bf16 (3*16*256*2 = 24576 B), aliased post-GEMM by per-wave OB
    // slices (8 waves * 16*36*4 = 18432 B). One barrier separates the uses.
    __shared__ __align__(16) char lds_raw[3 * BM * D_DIM * 2];
    __shared__ float lds_z[3][BM];
#define LDS_A ((unsigned short (*)[BM][D_DIM])lds_raw)

    const int tid  = threadIdx.x;
    const int wave = tid >> 6;                    // 0..7
    const int lane = tid & 63;
    const int b    = blockIdx.x >> 6;             // dialogue 0..127
    const int t0   = (blockIdx.x & (NTILES - 1)) * BM;

    // ---- gate weights for this lane's 4 k-values (L1-hot) ----
    const int k0 = lane * 4;
    float4 gav0 = *(const float4*)(wav + k0);
    float4 gav1 = *(const float4*)(wav + 256 + k0);
    float4 gav2 = *(const float4*)(wav + 512 + k0);
    float4 gal0 = *(const float4*)(wal + k0);
    float4 gal1 = *(const float4*)(wal + 256 + k0);
    float4 gal2 = *(const float4*)(wal + 512 + k0);
    float4 gvl0 = *(const float4*)(wvl + k0);
    float4 gvl1 = *(const float4*)(wvl + 256 + k0);
    float4 gvl2 = *(const float4*)(wvl + 512 + k0);
    const float gbav = bav[0], gbal = bal[0], gbvl = bvl[0];

    // ---------------- stage + fused gates: wave handles rows {wave, wave+8} ----
    const int swz  = (wave & 7) << 4;
    const int boff = (lane * 8) ^ swz;
#pragma unroll
    for (int i = 0; i < BM / 8; ++i) {
        const int row = wave + 8 * i;
        const size_t gbase = ((size_t)(t0 + row) * B_DLG + b) * D_DIM + lane * 4;
        float4 fa = *(const float4*)(a + gbase);
        float4 fv = *(const float4*)(v + gbase);
        float4 fl = *(const float4*)(l + gbase);

        ushort4 pa, pv, pl;
        pa.x = f_to_bfbits(fa.x); pa.y = f_to_bfbits(fa.y);
        pa.z = f_to_bfbits(fa.z); pa.w = f_to_bfbits(fa.w);
        pv.x = f_to_bfbits(fv.x); pv.y = f_to_bfbits(fv.y);
        pv.z = f_to_bfbits(fv.z); pv.w = f_to_bfbits(fv.w);
        pl.x = f_to_bfbits(fl.x); pl.y = f_to_bfbits(fl.y);
        pl.z = f_to_bfbits(fl.z); pl.w = f_to_bfbits(fl.w);
        *(ushort4*)((char*)&LDS_A[0][row][0] + boff) = pa;
        *(ushort4*)((char*)&LDS_A[1][row][0] + boff) = pv;
        *(ushort4*)((char*)&LDS_A[2][row][0] + boff) = pl;

        float4 pav, pal, pvl;
        pav.x = fa.x * fv.x; pav.y = fa.y * fv.y; pav.z = fa.z * fv.z; pav.w = fa.w * fv.w;
        pal.x = fa.x * fl.x; pal.y = fa.y * fl.y; pal.z = fa.z * fl.z; pal.w = fa.w * fl.w;
        pvl.x = fv.x * fl.x; pvl.y = fv.y * fl.y; pvl.z = fv.z * fl.z; pvl.w = fv.w * fl.w;
        float s_av = dot4(fa, gav0) + dot4(fv, gav1) + dot4(pav, gav2);
        float s_al = dot4(fa, gal0) + dot4(fl, gal1) + dot4(pal, gal2);
        float s_vl = dot4(fv, gvl0) + dot4(fl, gvl1) + dot4(pvl, gvl2);
#pragma unroll
        for (int off = 1; off < 64; off <<= 1) {
            s_av += __shfl_xor(s_av, off);
            s_al += __shfl_xor(s_al, off);
            s_vl += __shfl_xor(s_vl, off);
        }
        if (lane == 0) {
            lds_z[0][row] = fast_sigmoid(s_av + gbav);
            lds_z[1][row] = fast_sigmoid(s_al + gbal);
            lds_z[2][row] = fast_sigmoid(s_vl + gbvl);
        }
    }
    __syncthreads();

    // ---------------- GEMM: wave owns 32 cols of each modality, 16 rows ------
    f32x4 acc[3][2];
#pragma unroll
    for (int m = 0; m < 3; ++m)
#pragma unroll
        for (int ct = 0; ct < 2; ++ct)
            acc[m][ct] = (f32x4){0.f, 0.f, 0.f, 0.f};

    const int l15 = lane & 15;
    const int kblk = lane >> 4;          // 0..3

#pragma unroll 2
    for (int ks = 0; ks < KSTEPS; ++ks) {
        int kbyte = ks * 64 + kblk * 16;
#pragma unroll
        for (int mod = 0; mod < 3; ++mod) {
            int bo = kbyte ^ ((l15 & 7) << 4);
            short8 afrag = *(const short8*)((const char*)&LDS_A[mod][l15][0] + bo);
#pragma unroll
            for (int ct = 0; ct < 2; ++ct) {
                // packed fragment: cg = wave*2 + ct, lane-linear 1KB read (L2-hot)
                const unsigned short* bp = wbf +
                    ((size_t)(((mod * 16 + wave * 2 + ct) * 8 + ks) * 64) + lane) * 8;
                short8 bfrag = *(const short8*)bp;
                acc[mod][ct] = __builtin_amdgcn_mfma_f32_16x16x32_bf16(
                    afrag, bfrag, acc[mod][ct], 0, 0, 0);
            }
        }
    }

    __syncthreads();   // all A-tile reads done -> OB may alias lds_raw

    // ---------------- epilogue: per-wave private OB -> full-line stores -------
    float* ob = (float*)lds_raw + wave * (BM * OBROW);   // 2304 B per wave
    const size_t rowbase = (size_t)b * L_SEQ + t0;
    const int col0 = wave * 32 + l15, col1 = wave * 32 + 16 + l15;
    const float bba0 = ba[col0], bba1 = ba[col1];
    const float bbv0 = bv[col0], bbv1 = bv[col1];
    const float bbl0 = bl[col0], bbl1 = bl[col1];

#pragma unroll
    for (int sec = 0; sec < 3; ++sec) {
#pragma unroll
        for (int ct = 0; ct < 2; ++ct) {
#pragma unroll
            for (int r = 0; r < 4; ++r) {
                const int row = kblk * 4 + r;
                float h1, h2;
                if (sec == 0) {        // z_av*ha + (1-z_av)*hv
                    h1 = fast_tanh(acc[0][ct][r] + (ct ? bba1 : bba0));
                    h2 = fast_tanh(acc[1][ct][r] + (ct ? bbv1 : bbv0));
                } else if (sec == 1) { // z_al*ha + (1-z_al)*hl
                    h1 = fast_tanh(acc[0][ct][r] + (ct ? bba1 : bba0));
                    h2 = fast_tanh(acc[2][ct][r] + (ct ? bbl1 : bbl0));
                } else {               // z_vl*hv + (1-z_vl)*hl
                    h1 = fast_tanh(acc[1][ct][r] + (ct ? bbv1 : bbv0));
                    h2 = fast_tanh(acc[2][ct][r] + (ct ? bbl1 : bbl0));
                }
                const float z = lds_z[sec][row];
                ob[row * OBROW + ct * 16 + l15] = z * h1 + (1.f - z) * h2;
            }
        }
        // same-wave LDS RAW across lanes: enforce completion + ordering
        asm volatile("s_waitcnt lgkmcnt(0)" ::: "memory");
        __builtin_amdgcn_sched_barrier(0);
        // 2 store instrs per wave per sec; each 8-lane group fully covers
        // one 128B line: base = row*3072 + sec*1024 + wave*128 (all 128-aligned)
#pragma unroll
        for (int q = 0; q < 2; ++q) {
            const int rt   = q * 8 + (lane >> 3);      // row 0..15
            const int colq = lane & 7;                 // float4 slot within 32 cols
            float4 val = *(const float4*)&ob[rt * OBROW + colq * 4];
            *(float4*)(out + (rowbase + rt) * (3 * D_DIM)
                           + sec * D_DIM + wave * 32 + colq * 4) = val;
        }
    }
#undef LDS_A
}

extern "C" void kernel_launch(void* const* d_in, const int* in_sizes, int n_in,
                              void* d_out, int out_size, void* d_ws, size_t ws_size,
                              hipStream_t stream) {
    const float* a   = (const float*)d_in[0];
    const float* v   = (const float*)d_in[1];
    const float* l   = (const float*)d_in[2];
    // d_in[3] = lengths (all == L, static shape -> unused)
    const float* Wa  = (const float*)d_in[4];
    const float* ba  = (const float*)d_in[5];
    const float* Wv  = (const float*)d_in[6];
    const float* bv  = (const float*)d_in[7];
    const float* Wl  = (const float*)d_in[8];
    const float* bl  = (const float*)d_in[9];
    const float* Wav = (const float*)d_in[10];
    const float* bav = (const float*)d_in[11];
    const float* Wal = (const float*)d_in[12];
    const float* bal = (const float*)d_in[13];
    const float* Wvl = (const float*)d_in[14];
    const float* bvl = (const float*)d_in[15];
    float* out = (float*)d_out;

    unsigned short* wb = (unsigned short*)d_ws;   // needs 3*65536*2 = 384 KiB

    hipLaunchKernelGGL(wconv_kernel, dim3(96), dim3(256), 0, stream, Wa, Wv, Wl, wb);
    hipLaunchKernelGGL(fused_kernel, dim3(NBLK), dim3(THREADS), 0, stream,
                       a, v, l, wb, ba, bv, bl, Wav, bav, Wal, bal, Wvl, bvl, out);
}